// Round 3
// baseline (427.955 us; speedup 1.0000x reference)
//
#include <hip/hip_runtime.h>
#include <hip/hip_bf16.h>
#include <stdint.h>

#define M_DIM 4096
#define N_DIM 4096
#define K_DIM 4096
#define BM 128
#define BN 128
#define BK 64

typedef float f32x4 __attribute__((ext_vector_type(4)));
typedef __bf16 bf16x8 __attribute__((ext_vector_type(8)));
typedef float f4 __attribute__((ext_vector_type(4)));
typedef unsigned int u32x4 __attribute__((ext_vector_type(4)));
typedef unsigned short u16x4 __attribute__((ext_vector_type(4)));

__device__ __forceinline__ uint16_t f32_to_bf16_rn(float f) {
  uint32_t u = __float_as_uint(f);
  u += 0x7fffu + ((u >> 16) & 1u);
  return (uint16_t)(u >> 16);
}

// ---------- conversion: W -> sign(W) in bf16 ----------
__global__ void convert_w_kernel(const u32x4* __restrict__ w4,
                                 u16x4* __restrict__ s4, int n4) {
  int idx = blockIdx.x * blockDim.x + threadIdx.x;
  int stride = gridDim.x * blockDim.x;
  for (int i = idx; i < n4; i += stride) {
    u32x4 v = w4[i];
    u16x4 o;
#pragma unroll
    for (int j = 0; j < 4; ++j) {
      uint32_t b = v[j];
      o[j] = ((b & 0x7fffffffu) == 0u)
                 ? (uint16_t)0
                 : (uint16_t)(0x3F80u | ((b >> 16) & 0x8000u));
    }
    s4[i] = o;
  }
}

// ---------- conversion: x -> x_hi (bf16) + x_lo (bf16 of residual) ----------
__global__ void convert_x_kernel(const f4* __restrict__ x4,
                                 u16x4* __restrict__ hi4,
                                 u16x4* __restrict__ lo4, int n4) {
  int idx = blockIdx.x * blockDim.x + threadIdx.x;
  int stride = gridDim.x * blockDim.x;
  for (int i = idx; i < n4; i += stride) {
    f4 v = x4[i];
    u16x4 h, l;
#pragma unroll
    for (int j = 0; j < 4; ++j) {
      uint16_t hb = f32_to_bf16_rn(v[j]);
      float r = v[j] - __uint_as_float((uint32_t)hb << 16);
      h[j] = hb;
      l[j] = f32_to_bf16_rn(r);
    }
    hi4[i] = h;
    lo4[i] = l;
  }
}

// ---------- async global -> LDS, 16B per lane ----------
__device__ __forceinline__ void gload_lds16(const void* g, void* l) {
  __builtin_amdgcn_global_load_lds(
      (__attribute__((address_space(1))) void*)(g),
      (__attribute__((address_space(3))) void*)(l),
      16, 0, 0);
}

// ---------- main GEMM: out = (x_hi + x_lo) @ S^T + bias ----------
// A: [M][K] bf16 row-major (hi, lo). B: S [N][K] bf16 row-major (B^T layout).
__launch_bounds__(256, 3)
__global__ void bingemm_kernel(const uint16_t* __restrict__ Ahi,
                               const uint16_t* __restrict__ Alo,
                               const uint16_t* __restrict__ Bs,
                               const float* __restrict__ bias,
                               float* __restrict__ out) {
  __shared__ uint16_t sAh[BM * BK];
  __shared__ uint16_t sAl[BM * BK];
  __shared__ uint16_t sB[BN * BK];

  const int t = threadIdx.x;
  const int lane = t & 63;
  const int wave = t >> 6;
  const int wr = (wave >> 1) * 64;  // wave's row offset in tile
  const int wc = (wave & 1) * 64;   // wave's col offset in tile
  const int bm = blockIdx.y * BM;
  const int bn = blockIdx.x * BN;

  // staging: thread t, issue i -> row (i*32 + t/8), col (t%8)*8 of the tile
  const int srow = t >> 3;
  const int scol = (t & 7) * 8;
  const uint16_t* gAh = Ahi + (size_t)(bm + srow) * K_DIM + scol;
  const uint16_t* gAl = Alo + (size_t)(bm + srow) * K_DIM + scol;
  const uint16_t* gB = Bs + (size_t)(bn + srow) * K_DIM + scol;

  f32x4 acc[4][4];
#pragma unroll
  for (int i = 0; i < 4; ++i)
#pragma unroll
    for (int j = 0; j < 4; ++j) acc[i][j] = (f32x4){0.f, 0.f, 0.f, 0.f};

  const int r15 = lane & 15;
  const int kgrp = (lane >> 4) * 8;

  for (int kt = 0; kt < K_DIM; kt += BK) {
#pragma unroll
    for (int i = 0; i < 4; ++i) {
      gload_lds16(gAh + kt + i * 32 * K_DIM, &sAh[t * 8 + i * 2048]);
      gload_lds16(gAl + kt + i * 32 * K_DIM, &sAl[t * 8 + i * 2048]);
      gload_lds16(gB + kt + i * 32 * K_DIM, &sB[t * 8 + i * 2048]);
    }
    __syncthreads();

#pragma unroll
    for (int ks = 0; ks < 2; ++ks) {
      const int ko = ks * 32 + kgrp;
      bf16x8 ah[4], al[4], bb[4];
#pragma unroll
      for (int i = 0; i < 4; ++i) {
        ah[i] = *(const bf16x8*)&sAh[(wr + i * 16 + r15) * BK + ko];
        al[i] = *(const bf16x8*)&sAl[(wr + i * 16 + r15) * BK + ko];
        bb[i] = *(const bf16x8*)&sB[(wc + i * 16 + r15) * BK + ko];
      }
#pragma unroll
      for (int mi = 0; mi < 4; ++mi)
#pragma unroll
        for (int ni = 0; ni < 4; ++ni) {
          acc[mi][ni] = __builtin_amdgcn_mfma_f32_16x16x32_bf16(
              ah[mi], bb[ni], acc[mi][ni], 0, 0, 0);
          acc[mi][ni] = __builtin_amdgcn_mfma_f32_16x16x32_bf16(
              al[mi], bb[ni], acc[mi][ni], 0, 0, 0);
        }
    }
    __syncthreads();
  }

  // epilogue: C/D layout col = lane&15, row = (lane>>4)*4 + reg  [m89/m91]
  const int rowg = (lane >> 4) * 4;
#pragma unroll
  for (int ni = 0; ni < 4; ++ni) {
    const int col = bn + wc + ni * 16 + r15;
    const float bv = bias[col];
#pragma unroll
    for (int mi = 0; mi < 4; ++mi) {
      const int row0 = bm + wr + mi * 16 + rowg;
#pragma unroll
      for (int i = 0; i < 4; ++i)
        out[(size_t)(row0 + i) * N_DIM + col] = acc[mi][ni][i] + bv;
    }
  }
}

// ---------- fallback (only if workspace is too small): fp32 tiled ----------
__global__ void fallback_gemm(const float* __restrict__ x,
                              const float* __restrict__ w,
                              const float* __restrict__ bias,
                              float* __restrict__ out) {
  __shared__ float sx[16][17];
  __shared__ float sw[16][17];
  int tx = threadIdx.x & 15, ty = threadIdx.x >> 4;
  int m = blockIdx.y * 16 + ty;
  int n = blockIdx.x * 16 + tx;
  float acc = 0.f;
  for (int k0 = 0; k0 < K_DIM; k0 += 16) {
    sx[ty][tx] = x[(size_t)m * K_DIM + k0 + tx];
    float wv = w[(size_t)(blockIdx.x * 16 + ty) * K_DIM + k0 + tx];
    sw[ty][tx] = (wv > 0.f) ? 1.f : ((wv < 0.f) ? -1.f : 0.f);
    __syncthreads();
#pragma unroll
    for (int kk = 0; kk < 16; ++kk) acc += sx[ty][kk] * sw[tx][kk];
    __syncthreads();
  }
  out[(size_t)m * N_DIM + n] = acc + bias[n];
}

extern "C" void kernel_launch(void* const* d_in, const int* in_sizes, int n_in,
                              void* d_out, int out_size, void* d_ws,
                              size_t ws_size, hipStream_t stream) {
  const float* x = (const float*)d_in[0];
  const float* w = (const float*)d_in[1];
  const float* bias = (const float*)d_in[2];
  float* out = (float*)d_out;

  const size_t elems = (size_t)N_DIM * K_DIM;  // == M*K
  const size_t need = elems * 2u * 3u;         // S + x_hi + x_lo, bf16 each

  if (ws_size < need) {
    dim3 grid(N_DIM / 16, M_DIM / 16);
    fallback_gemm<<<grid, 256, 0, stream>>>(x, w, bias, out);
    return;
  }

  uint16_t* Sb = (uint16_t*)d_ws;
  uint16_t* Ahi = Sb + elems;
  uint16_t* Alo = Ahi + elems;

  const int n4 = (int)(elems / 4);
  convert_w_kernel<<<2048, 256, 0, stream>>>((const u32x4*)w, (u16x4*)Sb, n4);
  convert_x_kernel<<<2048, 256, 0, stream>>>((const f4*)x, (u16x4*)Ahi,
                                             (u16x4*)Alo, n4);

  dim3 grid(N_DIM / BN, M_DIM / BM);
  bingemm_kernel<<<grid, 256, 0, stream>>>(Ahi, Alo, Sb, bias, out);
}

// Round 4
// 402.837 us; speedup vs baseline: 1.0624x; 1.0624x over previous
//
#include <hip/hip_runtime.h>
#include <hip/hip_bf16.h>
#include <stdint.h>

#define M_DIM 4096
#define N_DIM 4096
#define K_DIM 4096
#define NT 128  // K-tiles of 64 over concatenated K = 8192 (hi | lo)

typedef float f32x4 __attribute__((ext_vector_type(4)));
typedef __bf16 bf16x8 __attribute__((ext_vector_type(8)));
typedef float f4 __attribute__((ext_vector_type(4)));
typedef unsigned int u32x4 __attribute__((ext_vector_type(4)));
typedef unsigned short u16x4 __attribute__((ext_vector_type(4)));

__device__ __forceinline__ uint16_t f32_to_bf16_rn(float f) {
  uint32_t u = __float_as_uint(f);
  u += 0x7fffu + ((u >> 16) & 1u);
  return (uint16_t)(u >> 16);
}

// ---------- W -> sign(W) in bf16 (exact: -1/0/+1) ----------
__global__ void convert_w_kernel(const u32x4* __restrict__ w4,
                                 u16x4* __restrict__ s4, int n4) {
  int idx = blockIdx.x * blockDim.x + threadIdx.x;
  int stride = gridDim.x * blockDim.x;
  for (int i = idx; i < n4; i += stride) {
    u32x4 v = w4[i];
    u16x4 o;
#pragma unroll
    for (int j = 0; j < 4; ++j) {
      uint32_t b = v[j];
      o[j] = ((b & 0x7fffffffu) == 0u)
                 ? (uint16_t)0
                 : (uint16_t)(0x3F80u | ((b >> 16) & 0x8000u));
    }
    s4[i] = o;
  }
}

// ---------- x -> A' = [x_hi | x_lo] rows of 8192 bf16 ----------
__global__ void convert_x_kernel(const f4* __restrict__ x4,
                                 uint16_t* __restrict__ Ab, int n4) {
  int idx = blockIdx.x * blockDim.x + threadIdx.x;
  int stride = gridDim.x * blockDim.x;
  for (int i = idx; i < n4; i += stride) {
    f4 v = x4[i];
    u16x4 h, l;
#pragma unroll
    for (int j = 0; j < 4; ++j) {
      uint16_t hb = f32_to_bf16_rn(v[j]);
      float r = v[j] - __uint_as_float((uint32_t)hb << 16);
      h[j] = hb;
      l[j] = f32_to_bf16_rn(r);
    }
    int flat = i * 4;
    int m = flat >> 12;       // / 4096
    int k = flat & 4095;
    *(u16x4*)&Ab[(size_t)m * 8192 + k] = h;
    *(u16x4*)&Ab[(size_t)m * 8192 + 4096 + k] = l;
  }
}

__device__ __forceinline__ void gload_lds16(const void* g, void* l) {
  __builtin_amdgcn_global_load_lds(
      (__attribute__((address_space(1))) void*)(g),
      (__attribute__((address_space(3))) void*)(l),
      16, 0, 0);
}

// ---------------- 256x256 8-phase GEMM, K = 8192 ----------------
// A': [4096][8192] bf16 (hi|lo). B: S [4096][4096] bf16 (B^T layout, wrap k).
// 8 waves (2M x 4N), per-wave 128x64 out, BK=64, LDS 128KB double-buffered.
__global__ __launch_bounds__(512, 2)
void bingemm8(const uint16_t* __restrict__ Ab, const uint16_t* __restrict__ Bs,
              const float* __restrict__ bias, float* __restrict__ out) {
  __shared__ uint16_t sA[2][2][8192];  // [dbuf][half: rows 0-127 / 128-255]
  __shared__ uint16_t sB[2][2][8192];  // [dbuf][half: cols 0-127 / 128-255]

  const int t = threadIdx.x;
  const int lane = t & 63;
  const int w = t >> 6;
  const int r15 = lane & 15;

  // XCD-aware bijective swizzle: 256 blocks, 32 per XCD
  const int bid = blockIdx.x;
  const int swz = (bid & 7) * 32 + (bid >> 3);
  const int bm = (swz >> 4) * 256;
  const int bn = (swz & 15) * 256;

  // ---- staging addressing (inverse-swizzled global source, linear LDS dest)
  const int srow = t >> 3;  // 0..63 (+64 for second issue)
  const int scol = (((t & 7) ^ (srow & 7)) * 8);  // swizzled source col (elems)
  const size_t aThr = (size_t)(bm + srow) * 8192 + scol;
  const size_t bThr = (size_t)(bn + srow) * 4096 + scol;

#define STAGE_A(KT, HH, BUF)                                        \
  do {                                                              \
    const uint16_t* g = Ab + aThr + (size_t)(HH) * 128 * 8192 +     \
                        (size_t)(KT) * 64;                          \
    gload_lds16(g, &sA[BUF][HH][t * 8]);                            \
    gload_lds16(g + (size_t)64 * 8192, &sA[BUF][HH][t * 8 + 4096]); \
  } while (0)
#define STAGE_B(KT, HH, BUF)                                        \
  do {                                                              \
    const uint16_t* g = Bs + bThr + (size_t)(HH) * 128 * 4096 +     \
                        (size_t)((KT) & 63) * 64;                   \
    gload_lds16(g, &sB[BUF][HH][t * 8]);                            \
    gload_lds16(g + (size_t)64 * 4096, &sB[BUF][HH][t * 8 + 4096]); \
  } while (0)

  // ---- fragment-read addressing (swizzled)
  const int klane = lane >> 4;                       // 0..3
  const int cb0 = (klane * 16) ^ ((lane & 7) << 4);  // byte col, ks=0
  const int whA = w >> 2;                            // A half
  const int whB = (w & 3) >> 1;                      // B half
  const int wcl = (w & 1) * 64;                      // B row base within half
  const int eA0 = r15 * 64 + (cb0 >> 1);             // elem offsets
  const int eA1 = eA0 ^ 32;
  const int eB0 = (wcl + r15) * 64 + (cb0 >> 1);
  const int eB1 = eB0 ^ 32;

  bf16x8 rA[4][2], rB[4][2];
  f32x4 acc[8][4];
#pragma unroll
  for (int m = 0; m < 8; ++m)
#pragma unroll
    for (int n = 0; n < 4; ++n) acc[m][n] = (f32x4){0.f, 0.f, 0.f, 0.f};

#define LOAD_A(BUF, MOFF)                                            \
  {                                                                  \
    _Pragma("unroll") for (int m = 0; m < 4; ++m) {                  \
      rA[m][0] = *(const bf16x8*)&sA[BUF][whA][eA0 + ((MOFF) + m) * 1024]; \
      rA[m][1] = *(const bf16x8*)&sA[BUF][whA][eA1 + ((MOFF) + m) * 1024]; \
    }                                                                \
  }
#define LOAD_B(BUF, NB)                                              \
  {                                                                  \
    _Pragma("unroll") for (int n = 0; n < 2; ++n) {                  \
      rB[(NB) + n][0] = *(const bf16x8*)&sB[BUF][whB][eB0 + ((NB) + n) * 1024]; \
      rB[(NB) + n][1] = *(const bf16x8*)&sB[BUF][whB][eB1 + ((NB) + n) * 1024]; \
    }                                                                \
  }
#define MFMA_Q(MB, NB)                                               \
  {                                                                  \
    _Pragma("unroll") for (int mm = 0; mm < 4; ++mm)                 \
    _Pragma("unroll") for (int nn = 0; nn < 2; ++nn)                 \
    _Pragma("unroll") for (int ks = 0; ks < 2; ++ks)                 \
      acc[(MB) + mm][(NB) + nn] = __builtin_amdgcn_mfma_f32_16x16x32_bf16( \
          rA[mm][ks], rB[(NB) + nn][ks], acc[(MB) + mm][(NB) + nn], 0, 0, 0); \
  }
#define PH_PRE()                                        \
  __builtin_amdgcn_s_barrier();                         \
  asm volatile("s_waitcnt lgkmcnt(0)" ::: "memory");    \
  __builtin_amdgcn_sched_barrier(0);                    \
  __builtin_amdgcn_s_setprio(1);
#define PH_POST()                                       \
  __builtin_amdgcn_s_setprio(0);                        \
  __builtin_amdgcn_s_barrier();
#define PH_POST_VM()                                    \
  __builtin_amdgcn_s_setprio(0);                        \
  asm volatile("s_waitcnt vmcnt(4)" ::: "memory");      \
  __builtin_amdgcn_s_barrier();

  // ---- prologue: tile0 (all 4 halves) + tile1 (B.h0, A.h0) = 12 loads
  STAGE_B(0, 0, 0);
  STAGE_A(0, 0, 0);
  STAGE_B(0, 1, 0);
  STAGE_A(0, 1, 0);
  STAGE_B(1, 0, 1);
  STAGE_A(1, 0, 1);
  asm volatile("s_waitcnt vmcnt(4)" ::: "memory");  // tile0 landed
  __builtin_amdgcn_s_barrier();

  for (int i = 0; i < NT / 2; ++i) {
    const int t1 = 2 * i + 1;
    const int tp0 = (2 * i + 2 < NT) ? (2 * i + 2) : (NT - 1);
    const int tp1 = (2 * i + 3 < NT) ? (2 * i + 3) : (NT - 1);
    // ---- tile 2i from buf0 ----
    // p1: Q(0,0)
    LOAD_A(0, 0);
    LOAD_B(0, 0);
    STAGE_B(t1, 1, 1);
    PH_PRE();
    MFMA_Q(0, 0);
    PH_POST();
    // p2: Q(0,1)
    LOAD_B(0, 2);
    STAGE_A(t1, 1, 1);
    PH_PRE();
    MFMA_Q(0, 2);
    PH_POST();
    // p3: Q(1,1)
    LOAD_A(0, 4);
    STAGE_B(tp0, 0, 0);
    PH_PRE();
    MFMA_Q(4, 2);
    PH_POST();
    // p4: Q(1,0)  [+vmcnt: tile 2i+1 confirmed]
    STAGE_A(tp0, 0, 0);
    PH_PRE();
    MFMA_Q(4, 0);
    PH_POST_VM();
    // ---- tile 2i+1 from buf1 ----
    // p5
    LOAD_A(1, 0);
    LOAD_B(1, 0);
    STAGE_B(tp0, 1, 0);
    PH_PRE();
    MFMA_Q(0, 0);
    PH_POST();
    // p6
    LOAD_B(1, 2);
    STAGE_A(tp0, 1, 0);
    PH_PRE();
    MFMA_Q(0, 2);
    PH_POST();
    // p7
    LOAD_A(1, 4);
    STAGE_B(tp1, 0, 1);
    PH_PRE();
    MFMA_Q(4, 2);
    PH_POST();
    // p8  [+vmcnt: tile 2i+2 confirmed]
    STAGE_A(tp1, 0, 1);
    PH_PRE();
    MFMA_Q(4, 0);
    PH_POST_VM();
  }

  asm volatile("s_waitcnt vmcnt(0)" ::: "memory");  // drain dummy prefetches

  // ---- epilogue: C/D layout col=lane&15, row=(lane>>4)*4+reg [m89/m91]
  const int rowg = (lane >> 4) * 4;
#pragma unroll
  for (int n = 0; n < 4; ++n) {
    const int col = bn + (w & 3) * 64 + n * 16 + r15;
    const float bv = bias[col];
#pragma unroll
    for (int m = 0; m < 8; ++m) {
      const int row0 = bm + (w >> 2) * 128 + m * 16 + rowg;
#pragma unroll
      for (int k = 0; k < 4; ++k)
        out[(size_t)(row0 + k) * N_DIM + col] = acc[m][n][k] + bv;
    }
  }
}

// ---------- fallback (workspace too small): fp32 tiled ----------
__global__ void fallback_gemm(const float* __restrict__ x,
                              const float* __restrict__ w,
                              const float* __restrict__ bias,
                              float* __restrict__ out) {
  __shared__ float sx[16][17];
  __shared__ float sw[16][17];
  int tx = threadIdx.x & 15, ty = threadIdx.x >> 4;
  int m = blockIdx.y * 16 + ty;
  int n = blockIdx.x * 16 + tx;
  float acc = 0.f;
  for (int k0 = 0; k0 < K_DIM; k0 += 16) {
    sx[ty][tx] = x[(size_t)m * K_DIM + k0 + tx];
    float wv = w[(size_t)(blockIdx.x * 16 + ty) * K_DIM + k0 + tx];
    sw[ty][tx] = (wv > 0.f) ? 1.f : ((wv < 0.f) ? -1.f : 0.f);
    __syncthreads();
#pragma unroll
    for (int kk = 0; kk < 16; ++kk) acc += sx[ty][kk] * sw[tx][kk];
    __syncthreads();
  }
  out[(size_t)m * N_DIM + n] = acc + bias[n];
}

extern "C" void kernel_launch(void* const* d_in, const int* in_sizes, int n_in,
                              void* d_out, int out_size, void* d_ws,
                              size_t ws_size, hipStream_t stream) {
  const float* x = (const float*)d_in[0];
  const float* w = (const float*)d_in[1];
  const float* bias = (const float*)d_in[2];
  float* out = (float*)d_out;

  const size_t elems = (size_t)N_DIM * K_DIM;  // 16.7M
  const size_t need = elems * 2u * 3u;         // Sb(2B) + A'(4B worth) = 96MB

  if (ws_size < need) {
    dim3 grid(N_DIM / 16, M_DIM / 16);
    fallback_gemm<<<grid, 256, 0, stream>>>(x, w, bias, out);
    return;
  }

  uint16_t* Sb = (uint16_t*)d_ws;      // [4096][4096] sign(W) bf16
  uint16_t* Ab = Sb + elems;           // [4096][8192] (x_hi | x_lo) bf16

  const int n4 = (int)(elems / 4);
  convert_w_kernel<<<4096, 256, 0, stream>>>((const u32x4*)w, (u16x4*)Sb, n4);
  convert_x_kernel<<<4096, 256, 0, stream>>>((const f4*)x, Ab, n4);

  bingemm8<<<dim3(256), 512, 0, stream>>>(Ab, Sb, bias, out);
}

// Round 5
// 379.484 us; speedup vs baseline: 1.1277x; 1.0615x over previous
//
#include <hip/hip_runtime.h>
#include <hip/hip_bf16.h>
#include <stdint.h>

#define M_DIM 4096
#define N_DIM 4096
#define K_DIM 4096
#define NT 128  // K-tiles of 64 over concatenated K = 8192 (hi | lo)

typedef float f32x4 __attribute__((ext_vector_type(4)));
typedef __bf16 bf16x8 __attribute__((ext_vector_type(8)));
typedef float f4 __attribute__((ext_vector_type(4)));
typedef unsigned int u32x4 __attribute__((ext_vector_type(4)));
typedef unsigned short u16x4 __attribute__((ext_vector_type(4)));

__device__ __forceinline__ uint16_t f32_to_bf16_rn(float f) {
  uint32_t u = __float_as_uint(f);
  u += 0x7fffu + ((u >> 16) & 1u);
  return (uint16_t)(u >> 16);
}

// ---------- W -> sign(W) in bf16 (exact: -1/0/+1) ----------
__global__ void convert_w_kernel(const u32x4* __restrict__ w4,
                                 u16x4* __restrict__ s4, int n4) {
  int idx = blockIdx.x * blockDim.x + threadIdx.x;
  int stride = gridDim.x * blockDim.x;
  for (int i = idx; i < n4; i += stride) {
    u32x4 v = w4[i];
    u16x4 o;
#pragma unroll
    for (int j = 0; j < 4; ++j) {
      uint32_t b = v[j];
      o[j] = ((b & 0x7fffffffu) == 0u)
                 ? (uint16_t)0
                 : (uint16_t)(0x3F80u | ((b >> 16) & 0x8000u));
    }
    s4[i] = o;
  }
}

// ---------- x -> A' = [x_hi | x_lo] rows of 8192 bf16 ----------
__global__ void convert_x_kernel(const f4* __restrict__ x4,
                                 uint16_t* __restrict__ Ab, int n4) {
  int idx = blockIdx.x * blockDim.x + threadIdx.x;
  int stride = gridDim.x * blockDim.x;
  for (int i = idx; i < n4; i += stride) {
    f4 v = x4[i];
    u16x4 h, l;
#pragma unroll
    for (int j = 0; j < 4; ++j) {
      uint16_t hb = f32_to_bf16_rn(v[j]);
      float r = v[j] - __uint_as_float((uint32_t)hb << 16);
      h[j] = hb;
      l[j] = f32_to_bf16_rn(r);
    }
    int flat = i * 4;
    int m = flat >> 12;       // / 4096
    int k = flat & 4095;
    *(u16x4*)&Ab[(size_t)m * 8192 + k] = h;
    *(u16x4*)&Ab[(size_t)m * 8192 + 4096 + k] = l;
  }
}

__device__ __forceinline__ void gload_lds16(const void* g, void* l) {
  __builtin_amdgcn_global_load_lds(
      (__attribute__((address_space(1))) void*)(g),
      (__attribute__((address_space(3))) void*)(l),
      16, 0, 0);
}

// ---------------- 256x256 8-phase GEMM, K = 8192 ----------------
// A': [4096][8192] bf16 (hi|lo). B: S [4096][4096] bf16 (B^T layout, wrap k).
// 8 waves (2M x 4N), per-wave 128x64 out, BK=64, LDS 128KB double-buffered.
// Balanced phases: 8/8/4/4 ds_reads, 16 independent MFMAs each, 1 stage/phase.
__global__ __launch_bounds__(512, 2)
void bingemm8(const uint16_t* __restrict__ Ab, const uint16_t* __restrict__ Bs,
              const float* __restrict__ bias, float* __restrict__ out) {
  __shared__ uint16_t sA[2][2][8192];  // [dbuf][half: rows 0-127 / 128-255]
  __shared__ uint16_t sB[2][2][8192];  // [dbuf][half: cols 0-127 / 128-255]

  const int t = threadIdx.x;
  const int lane = t & 63;
  const int w = t >> 6;
  const int r15 = lane & 15;

  // XCD-aware bijective swizzle: 256 blocks, 32 per XCD
  const int bid = blockIdx.x;
  const int swz = (bid & 7) * 32 + (bid >> 3);
  const int bm = (swz >> 4) * 256;
  const int bn = (swz & 15) * 256;

  // ---- staging addressing (inverse-swizzled global source, linear LDS dest)
  const int srow = t >> 3;  // 0..63 (+64 for second issue)
  const int scol = (((t & 7) ^ (srow & 7)) * 8);  // swizzled source col (elems)
  const size_t aThr = (size_t)(bm + srow) * 8192 + scol;
  const size_t bThr = (size_t)(bn + srow) * 4096 + scol;

#define STAGE_A(KT, HH, BUF)                                        \
  do {                                                              \
    const uint16_t* g = Ab + aThr + (size_t)(HH) * 128 * 8192 +     \
                        (size_t)(KT) * 64;                          \
    gload_lds16(g, &sA[BUF][HH][t * 8]);                            \
    gload_lds16(g + (size_t)64 * 8192, &sA[BUF][HH][t * 8 + 4096]); \
  } while (0)
#define STAGE_B(KT, HH, BUF)                                        \
  do {                                                              \
    const uint16_t* g = Bs + bThr + (size_t)(HH) * 128 * 4096 +     \
                        (size_t)((KT) & 63) * 64;                   \
    gload_lds16(g, &sB[BUF][HH][t * 8]);                            \
    gload_lds16(g + (size_t)64 * 4096, &sB[BUF][HH][t * 8 + 4096]); \
  } while (0)

  // ---- fragment-read addressing (swizzled)
  const int klane = lane >> 4;                       // 0..3
  const int cb0 = (klane * 16) ^ ((lane & 7) << 4);  // byte col, ks=0
  const int whA = w >> 2;                            // A half
  const int whB = (w & 3) >> 1;                      // B half
  const int wcl = (w & 1) * 64;                      // B row base within half
  const int eA0 = r15 * 64 + (cb0 >> 1);             // elem offsets
  const int eA1 = eA0 ^ 32;                          // ks=1 slice
  const int eB0 = (wcl + r15) * 64 + (cb0 >> 1);
  const int eB1 = eB0 ^ 32;

  bf16x8 rAa[4], rAb[4], rBa[4], rBb[4];
  f32x4 acc[8][4];
#pragma unroll
  for (int m = 0; m < 8; ++m)
#pragma unroll
    for (int n = 0; n < 4; ++n) acc[m][n] = (f32x4){0.f, 0.f, 0.f, 0.f};

  // 4 reads: A rows (MOFF..MOFF+3), ks=0 -> rAa
#define LOAD_A0(BUF, MOFF)                                                 \
  {                                                                        \
    _Pragma("unroll") for (int m = 0; m < 4; ++m)                          \
        rAa[m] = *(const bf16x8*)&sA[BUF][whA][eA0 + ((MOFF) + m) * 1024]; \
  }
#define LOAD_A1(BUF, MOFF)                                                 \
  {                                                                        \
    _Pragma("unroll") for (int m = 0; m < 4; ++m)                          \
        rAb[m] = *(const bf16x8*)&sA[BUF][whA][eA1 + ((MOFF) + m) * 1024]; \
  }
#define LOAD_B0(BUF)                                                       \
  {                                                                        \
    _Pragma("unroll") for (int n = 0; n < 4; ++n)                          \
        rBa[n] = *(const bf16x8*)&sB[BUF][whB][eB0 + n * 1024];            \
  }
#define LOAD_B1(BUF)                                                       \
  {                                                                        \
    _Pragma("unroll") for (int n = 0; n < 4; ++n)                          \
        rBb[n] = *(const bf16x8*)&sB[BUF][whB][eB1 + n * 1024];            \
  }
  // 16 independent MFMAs: rows (MB..MB+3) x all 4 col-tiles, one k-slice
#define MFMA16(MB, RA, RB)                                                 \
  {                                                                        \
    _Pragma("unroll") for (int mm = 0; mm < 4; ++mm)                       \
    _Pragma("unroll") for (int nn = 0; nn < 4; ++nn)                       \
        acc[(MB) + mm][nn] = __builtin_amdgcn_mfma_f32_16x16x32_bf16(      \
            RA[mm], RB[nn], acc[(MB) + mm][nn], 0, 0, 0);                  \
  }
#define PH_PRE()                                        \
  __builtin_amdgcn_s_barrier();                         \
  asm volatile("s_waitcnt lgkmcnt(0)" ::: "memory");    \
  __builtin_amdgcn_sched_barrier(0);                    \
  __builtin_amdgcn_s_setprio(1);
#define PH_POST()                                       \
  __builtin_amdgcn_s_setprio(0);                        \
  __builtin_amdgcn_s_barrier();
#define PH_POST_VM()                                    \
  __builtin_amdgcn_s_setprio(0);                        \
  asm volatile("s_waitcnt vmcnt(4)" ::: "memory");      \
  __builtin_amdgcn_s_barrier();

  // ---- prologue: tile0 (B+A) into buf0, tile1 B into buf1 = 12 loads
  STAGE_B(0, 0, 0);
  STAGE_B(0, 1, 0);
  STAGE_A(0, 0, 0);
  STAGE_A(0, 1, 0);
  STAGE_B(1, 0, 1);
  STAGE_B(1, 1, 1);
  asm volatile("s_waitcnt vmcnt(4)" ::: "memory");  // tile0 landed
  __builtin_amdgcn_s_barrier();

  for (int i = 0; i < NT / 2; ++i) {
    const int t1 = 2 * i + 1;
    const int tp0 = (2 * i + 2 < NT) ? (2 * i + 2) : (NT - 1);
    const int tp1 = (2 * i + 3 < NT) ? (2 * i + 3) : (NT - 1);
    // ---- tile 2i from buf0 ----
    // p1: rows0-3 ks0 x all cols
    LOAD_A0(0, 0);
    LOAD_B0(0);
    STAGE_A(t1, 0, 1);
    PH_PRE();
    MFMA16(0, rAa, rBa);
    PH_POST();
    // p2: rows0-3 ks1
    LOAD_A1(0, 0);
    LOAD_B1(0);
    STAGE_A(t1, 1, 1);
    PH_PRE();
    MFMA16(0, rAb, rBb);
    PH_POST();
    // p3: rows4-7 ks0 (rBa still live)
    LOAD_A0(0, 4);
    STAGE_B(tp0, 0, 0);
    PH_PRE();
    MFMA16(4, rAa, rBa);
    PH_POST();
    // p4: rows4-7 ks1  [+vmcnt(4): t1 fully landed]
    LOAD_A1(0, 4);
    STAGE_B(tp0, 1, 0);
    PH_PRE();
    MFMA16(4, rAb, rBb);
    PH_POST_VM();
    // ---- tile 2i+1 from buf1 ----
    // p5
    LOAD_A0(1, 0);
    LOAD_B0(1);
    STAGE_A(tp0, 0, 0);
    PH_PRE();
    MFMA16(0, rAa, rBa);
    PH_POST();
    // p6
    LOAD_A1(1, 0);
    LOAD_B1(1);
    STAGE_A(tp0, 1, 0);
    PH_PRE();
    MFMA16(0, rAb, rBb);
    PH_POST();
    // p7
    LOAD_A0(1, 4);
    STAGE_B(tp1, 0, 1);
    PH_PRE();
    MFMA16(4, rAa, rBa);
    PH_POST();
    // p8  [+vmcnt(4): tile 2i+2 fully landed]
    LOAD_A1(1, 4);
    STAGE_B(tp1, 1, 1);
    PH_PRE();
    MFMA16(4, rAb, rBb);
    PH_POST_VM();
  }

  asm volatile("s_waitcnt vmcnt(0)" ::: "memory");  // drain tail prefetches

  // ---- epilogue: C/D layout col=lane&15, row=(lane>>4)*4+reg [m89/m91]
  const int rowg = (lane >> 4) * 4;
#pragma unroll
  for (int n = 0; n < 4; ++n) {
    const int col = bn + (w & 3) * 64 + n * 16 + r15;
    const float bv = bias[col];
#pragma unroll
    for (int m = 0; m < 8; ++m) {
      const int row0 = bm + (w >> 2) * 128 + m * 16 + rowg;
#pragma unroll
      for (int k = 0; k < 4; ++k)
        out[(size_t)(row0 + k) * N_DIM + col] = acc[m][n][k] + bv;
    }
  }
}

// ---------- fallback (workspace too small): fp32 tiled ----------
__global__ void fallback_gemm(const float* __restrict__ x,
                              const float* __restrict__ w,
                              const float* __restrict__ bias,
                              float* __restrict__ out) {
  __shared__ float sx[16][17];
  __shared__ float sw[16][17];
  int tx = threadIdx.x & 15, ty = threadIdx.x >> 4;
  int m = blockIdx.y * 16 + ty;
  int n = blockIdx.x * 16 + tx;
  float acc = 0.f;
  for (int k0 = 0; k0 < K_DIM; k0 += 16) {
    sx[ty][tx] = x[(size_t)m * K_DIM + k0 + tx];
    float wv = w[(size_t)(blockIdx.x * 16 + ty) * K_DIM + k0 + tx];
    sw[ty][tx] = (wv > 0.f) ? 1.f : ((wv < 0.f) ? -1.f : 0.f);
    __syncthreads();
#pragma unroll
    for (int kk = 0; kk < 16; ++kk) acc += sx[ty][kk] * sw[tx][kk];
    __syncthreads();
  }
  out[(size_t)m * N_DIM + n] = acc + bias[n];
}

extern "C" void kernel_launch(void* const* d_in, const int* in_sizes, int n_in,
                              void* d_out, int out_size, void* d_ws,
                              size_t ws_size, hipStream_t stream) {
  const float* x = (const float*)d_in[0];
  const float* w = (const float*)d_in[1];
  const float* bias = (const float*)d_in[2];
  float* out = (float*)d_out;

  const size_t elems = (size_t)N_DIM * K_DIM;  // 16.7M
  const size_t need = elems * 2u * 3u;         // Sb(2B) + A'(4B worth) = 96MB

  if (ws_size < need) {
    dim3 grid(N_DIM / 16, M_DIM / 16);
    fallback_gemm<<<grid, 256, 0, stream>>>(x, w, bias, out);
    return;
  }

  uint16_t* Sb = (uint16_t*)d_ws;      // [4096][4096] sign(W) bf16
  uint16_t* Ab = Sb + elems;           // [4096][8192] (x_hi | x_lo) bf16

  const int n4 = (int)(elems / 4);
  convert_w_kernel<<<4096, 256, 0, stream>>>((const u32x4*)w, (u16x4*)Sb, n4);
  convert_x_kernel<<<4096, 256, 0, stream>>>((const f4*)x, Ab, n4);

  bingemm8<<<dim3(256), 512, 0, stream>>>(Ab, Sb, bias, out);
}